// Round 9
// baseline (357.136 us; speedup 1.0000x reference)
//
#include <hip/hip_runtime.h>
#include <hip/hip_bf16.h>

// ModulatedConv2d B=16, Cin=Cout=512, 3x3, 64x64.
// out = deco[b,o] * conv2d(x*s[b,i], W*gain), weights shared across batch.
// Conv: 32x32x16 bf16 MFMA. Block = (bi, 64-o tile, 8-row tile), 8 waves;
// wave = 1 output row x 64o(2mi) x 64x(2ni), acc 2x2 f32x16 = 64 regs.
// A (weights) loaded DIRECTLY FROM GLOBAL to registers (L2/L3-resident,
// coalesced lane*16B) -> LDS carries only X: 18 ds_read_b128 per 36 MFMA.
// B-reads software-pipelined one MFMA-cluster ahead (distinct regs; the
// 64-reg acc leaves ~130 regs of headroom so the allocator keeps the
// pipeline instead of sinking reads -> LDS and MFMA pipes overlap).
//
// ws layout:
//   s    : f32[16*512]                 @ 0
//   deco : f32[16*512]                 @ 32768
//   q    : f32[512*512]                @ 65536
//   wb2  : bf16 frag-linear W          @ 1114112   (8 ot x 32 chunk x 18 (mi,t) x 64 lane x 16B)
//   xs2  : bf16 khalf-major X          @ 5832704   (16 b x 32 chunk x 64 y x 2 h x 64 xpos x 16B)

#define NCH 512

static constexpr float FC_GAIN_C = 0.04419417382415922f;   // 1/sqrt(512)
static constexpr float W_GAIN_C  = 0.014731391274719742f;  // 1/sqrt(512*9)

typedef float        f32x4  __attribute__((ext_vector_type(4)));
typedef float        f32x16 __attribute__((ext_vector_type(16)));
typedef short        s16x8  __attribute__((ext_vector_type(8)));
typedef unsigned int u32x4  __attribute__((ext_vector_type(4)));

__device__ __forceinline__ unsigned short f2bf(float f) {
    __hip_bfloat16 h = __float2bfloat16(f);
    return *reinterpret_cast<unsigned short*>(&h);
}

__device__ __forceinline__ void gld16(const void* g, void* l) {
    __builtin_amdgcn_global_load_lds(
        (const __attribute__((address_space(1))) unsigned int*)g,
        (__attribute__((address_space(3))) unsigned int*)(l), 16, 0, 0);
}

// ---------------- K1: s[b,i] = style[b,:] . fc_w[i,:] * FC_GAIN + fc_b[i] ----------------
__global__ void calc_s_kernel(const float* __restrict__ style,
                              const float* __restrict__ fc_w,
                              const float* __restrict__ fc_b,
                              float* __restrict__ s) {
    int gw   = (blockIdx.x * blockDim.x + threadIdx.x) >> 6;
    int lane = threadIdx.x & 63;
    int b = gw >> 9;
    int i = gw & 511;
    const float* st = style + b * NCH;
    const float* fw = fc_w + (size_t)i * NCH;
    float sum = 0.f;
    #pragma unroll
    for (int k = 0; k < NCH / 64; ++k)
        sum += st[lane + 64 * k] * fw[lane + 64 * k];
    #pragma unroll
    for (int off = 32; off >= 1; off >>= 1)
        sum += __shfl_xor(sum, off, 64);
    if (lane == 0)
        s[b * NCH + i] = sum * FC_GAIN_C + fc_b[i];
}

// ---------------- K2: q[o,i] and fragment-linear wb2 ------------------------------------
// wb2 unit: (((ot*32+chunk)*18 + mi*9 + t)*64 + lane)*8 + e
// content: W[o = ot*64 + mi*32 + (lane&31)][ci = chunk*16 + (lane>>5)*8 + e][tap t] * gain
__global__ void calc_q_wb2_kernel(const float* __restrict__ weight,
                                  float* __restrict__ q,
                                  unsigned short* __restrict__ wb2) {
    int o = blockIdx.x;        // 0..511
    int i = threadIdx.x;       // 0..511 (ci)
    int orel = o & 63, ot = o >> 6;
    int mi = orel >> 5, l31 = orel & 31;
    int chunk = i >> 4, kk = i & 15;
    int lane = (kk >> 3) * 32 + l31, e = kk & 7;
    const float* wp = weight + ((size_t)o * NCH + i) * 9;
    float qs = 0.f;
    #pragma unroll
    for (int t = 0; t < 9; ++t) {
        float v = wp[t] * W_GAIN_C;
        qs += v * v;
        wb2[((((size_t)(ot * 32 + chunk) * 18) + mi * 9 + t) * 64 + lane) * 8 + e] = f2bf(v);
    }
    q[(size_t)o * NCH + i] = qs;
}

// ---------------- K3: deco[b,o] = rsqrt( sum_i q[o,i]*s[b,i]^2 + 1e-8 ) -----------------
__global__ void calc_deco_kernel(const float* __restrict__ q,
                                 const float* __restrict__ s,
                                 float* __restrict__ deco) {
    int gw   = (blockIdx.x * blockDim.x + threadIdx.x) >> 6;
    int lane = threadIdx.x & 63;
    int b = gw >> 9;
    int o = gw & 511;
    const float* qp = q + (size_t)o * NCH;
    const float* sp = s + b * NCH;
    float sum = 0.f;
    #pragma unroll
    for (int k = 0; k < NCH / 64; ++k) {
        float sv = sp[lane + 64 * k];
        sum += qp[lane + 64 * k] * sv * sv;
    }
    #pragma unroll
    for (int off = 32; off >= 1; off >>= 1)
        sum += __shfl_xor(sum, off, 64);
    if (lane == 0)
        deco[b * NCH + o] = rsqrtf(sum + 1e-8f);
}

// ---------------- K4: xs2 = bf16(x * s), NCHW -> khalf-major slot layout ------------------
// xs2 unit: (((b*32+chunk)*64 + y)*2 + h)*64 + xpos ; content ch [chunk*16+h*8, +8) at (y,xpos)
__global__ __launch_bounds__(256)
void scale_x2_kernel(const float* __restrict__ x, const float* __restrict__ s,
                     unsigned short* __restrict__ xs2) {
    __shared__ float tlf[2][64][17];
    int blk = blockIdx.x;          // 512 = bi*32 + chunk
    int chunk = blk & 31, bi = blk >> 5;
    int t = threadIdx.x;
    int ch0 = chunk * 16;
    int cl = t >> 4, xq = (t & 15) * 4;
    float sv = s[bi * NCH + ch0 + cl];
    const float* xp = x + ((size_t)(bi * NCH + ch0 + cl)) * 4096 + xq;
    int p = t >> 7, tt = t & 127;
    int hf = tt >> 6, xpos = tt & 63;
    unsigned short* xout = xs2 + (size_t)(bi * 32 + chunk) * 64 * 2 * 64 * 8;
    for (int y2 = 0; y2 < 64; y2 += 2) {
        f32x4 a0 = *(const f32x4*)(xp + (size_t)y2 * 64);
        f32x4 a1 = *(const f32x4*)(xp + (size_t)(y2 + 1) * 64);
        #pragma unroll
        for (int j = 0; j < 4; ++j) {
            tlf[0][xq + j][cl] = a0[j] * sv;
            tlf[1][xq + j][cl] = a1[j] * sv;
        }
        __syncthreads();
        const float* src = &tlf[p][xpos][hf * 8];
        u32x4 v;
        #pragma unroll
        for (int j = 0; j < 4; ++j)
            v[j] = (unsigned)f2bf(src[2 * j]) | ((unsigned)f2bf(src[2 * j + 1]) << 16);
        *(u32x4*)(xout + (((size_t)(y2 + p) * 2 + hf) * 64 + xpos) * 8) = v;
        __syncthreads();
    }
}

// ---------------- K5: conv --------------------------------------------------------------
// LDS per buffer (X only): [10 rows][2 h][66 P][16B] = 21120 B. dbuf = 42240 B.
#define X_SH 10560   // shorts per X buffer

// 20 DMA ids over 8 waves: r_=id>>1 (window row 0..9), h=id&1
#define ISSUE(nc, XN)                                                              \
    {                                                                              \
        _Pragma("unroll") for (int j = 0; j < 3; ++j) {                            \
            int id = wave + j * 8;                                                 \
            if (id < 20) {                                                         \
                int r_ = id >> 1, hf = id & 1, gy = y0 - 1 + r_;                   \
                if (gy >= 0 && gy < 64)                                            \
                    gld16(xsrc + ((((size_t)(nc) * 64 + gy) * 2 + hf) * 64 + lane) * 16, \
                          (XN) + r_ * 1056 + hf * 528 + 8);                        \
            }                                                                      \
        }                                                                          \
    }

#define VMBAR()                                                                    \
    {                                                                              \
        asm volatile("s_waitcnt vmcnt(0)" ::: "memory");                           \
        __builtin_amdgcn_s_barrier();                                              \
        __builtin_amdgcn_sched_barrier(0);                                         \
    }

// B frags from LDS: 6 ds_read_b128, window row RR
#define LOADB(DST, XC, RR)                                                         \
    _Pragma("unroll") for (int dx = 0; dx < 3; ++dx)                               \
        _Pragma("unroll") for (int ni = 0; ni < 2; ++ni)                           \
            DST[dx][ni] = *(const s16x8*)((XC) + (RR) * 1056 + bofs[dx][ni]);

// A frags straight from GLOBAL (frag-linear wb2): 6 global_load_dwordx4
#define LOADAG(DST, NC, K)                                                         \
    _Pragma("unroll") for (int dx = 0; dx < 3; ++dx)                               \
        _Pragma("unroll") for (int mi = 0; mi < 2; ++mi)                           \
            DST[dx][mi] = *(const s16x8*)(wsg + ((((size_t)(NC) * 18 + mi * 9 + 3 * (K) + dx) * 64 + lane) << 3));

// 12-MFMA cluster (tap-row): acc[mi][ni] += A[dx][mi] * B[dx][ni]
#define MMA12(AV, BV)                                                              \
    __builtin_amdgcn_s_setprio(1);                                                 \
    _Pragma("unroll") for (int dx = 0; dx < 3; ++dx)                               \
        _Pragma("unroll") for (int mi = 0; mi < 2; ++mi)                           \
            _Pragma("unroll") for (int ni = 0; ni < 2; ++ni)                       \
                acc[mi][ni] = __builtin_amdgcn_mfma_f32_32x32x16_bf16(             \
                    AV[dx][mi], BV[dx][ni], acc[mi][ni], 0, 0, 0);                 \
    __builtin_amdgcn_s_setprio(0);

// one 16-ch chunk: 36 MFMA, 18 LDS reads (pipelined 1 cluster ahead), 18 VMEM A-loads
#define COMPUTE(XC, NC, ...)                                                       \
    {                                                                              \
        s16x8 A0[3][2], A1[3][2], A2[3][2];                                        \
        s16x8 B0[3][2], B1[3][2], B2[3][2];                                        \
        LOADAG(A0, NC, 0);                                                         \
        LOADAG(A1, NC, 1);                                                         \
        LOADB(B0, XC, wave + 0);                                                   \
        LOADB(B1, XC, wave + 1);                                                   \
        __VA_ARGS__;                                                               \
        MMA12(A0, B0);                                                             \
        LOADAG(A2, NC, 2);                                                         \
        LOADB(B2, XC, wave + 2);                                                   \
        MMA12(A1, B1);                                                             \
        MMA12(A2, B2);                                                             \
    }

__global__ __launch_bounds__(512, 2)
void conv_kernel(const unsigned short* __restrict__ xs2,
                 const unsigned short* __restrict__ wb2,
                 const float* __restrict__ deco,
                 float* __restrict__ out) {
    extern __shared__ unsigned short smem[];
    unsigned short* x0 = smem;
    unsigned short* x1 = smem + X_SH;

    int tid  = threadIdx.x;
    int lane = tid & 63, wave = tid >> 6;
    int r31  = lane & 31, hi = lane >> 5;

    int blk = blockIdx.x;
    int swz = (blk & 7) * 128 + (blk >> 3);    // XCD-chunked (1024 % 8 == 0, bijective)
    int bi = swz >> 6, ot = (swz >> 3) & 7, yt = swz & 7;
    int o0 = ot * 64, y0 = yt * 8;

    // zero X buffers once: halo granules (P=0,65) and out-of-image rows stay 0
    {
        u32x4 z = {0u, 0u, 0u, 0u};
        for (int idx = tid; idx < X_SH / 8; idx += 512) {
            *(u32x4*)(x0 + idx * 8) = z;
            *(u32x4*)(x1 + idx * 8) = z;
        }
    }
    __syncthreads();

    const unsigned short* wsg = wb2 + (size_t)ot * 32 * 18 * 64 * 8;
    const char* xsrc = (const char*)xs2 + (size_t)bi * 32 * 64 * 2 * 64 * 16;

    // lane-linear B read offsets (shorts): row term added per read
    int bofs[3][2];
    #pragma unroll
    for (int dx = 0; dx < 3; ++dx)
        #pragma unroll
        for (int ni = 0; ni < 2; ++ni)
            bofs[dx][ni] = hi * 528 + (r31 + dx + 32 * ni) * 8;

    f32x16 acc[2][2];
    #pragma unroll
    for (int mi = 0; mi < 2; ++mi)
        #pragma unroll
        for (int ni = 0; ni < 2; ++ni)
            #pragma unroll
            for (int k = 0; k < 16; ++k) acc[mi][ni][k] = 0.f;

    ISSUE(0, x0);

    #pragma unroll 1
    for (int c = 0; c < 32; c += 2) {
        VMBAR();                                   // chunk-c X landed everywhere
        COMPUTE(x0, c, ISSUE(c + 1, x1));
        VMBAR();
        COMPUTE(x1, c + 1, if (c + 2 < 32) ISSUE(c + 2, x0));
    }

    // epilogue: scale by deco, store f32
    const float* dcp = deco + bi * NCH + o0;
    int y = y0 + wave;
    #pragma unroll
    for (int mi = 0; mi < 2; ++mi) {
        #pragma unroll
        for (int rg = 0; rg < 16; ++rg) {
            int ol = mi * 32 + (rg & 3) + 8 * (rg >> 2) + 4 * hi;
            float dc = dcp[ol];
            float* orow = out + ((size_t)(bi * NCH + o0 + ol) * 64 + y) * 64 + r31;
            orow[0]  = acc[mi][0][rg] * dc;
            orow[32] = acc[mi][1][rg] * dc;
        }
    }
}

extern "C" void kernel_launch(void* const* d_in, const int* in_sizes, int n_in,
                              void* d_out, int out_size, void* d_ws, size_t ws_size,
                              hipStream_t stream) {
    const float* x      = (const float*)d_in[0];
    const float* style  = (const float*)d_in[1];
    const float* weight = (const float*)d_in[2];
    const float* fc_w   = (const float*)d_in[3];
    const float* fc_b   = (const float*)d_in[4];
    float* out = (float*)d_out;

    char* ws = (char*)d_ws;
    float* s    = (float*)(ws);
    float* deco = (float*)(ws + 32768);
    float* q    = (float*)(ws + 65536);
    unsigned short* wb2 = (unsigned short*)(ws + 1114112);
    unsigned short* xs2 = (unsigned short*)(ws + 5832704);

    (void)hipFuncSetAttribute((const void*)conv_kernel,
                              hipFuncAttributeMaxDynamicSharedMemorySize, 42240);

    calc_s_kernel<<<2048, 256, 0, stream>>>(style, fc_w, fc_b, s);
    calc_q_wb2_kernel<<<512, 512, 0, stream>>>(weight, q, wb2);
    calc_deco_kernel<<<2048, 256, 0, stream>>>(q, s, deco);
    scale_x2_kernel<<<512, 256, 0, stream>>>(x, s, xs2);
    conv_kernel<<<1024, 512, 42240, stream>>>(xs2, wb2, deco, out);
}

// Round 10
// 300.202 us; speedup vs baseline: 1.1897x; 1.1897x over previous
//
#include <hip/hip_runtime.h>
#include <hip/hip_bf16.h>

// ModulatedConv2d B=16, Cin=Cout=512, 3x3, 64x64.
// out = deco[b,o] * conv2d(x*s[b,i], W*gain), weights shared across batch.
// Conv: 32x32x16 bf16 MFMA. Block = (bi, 64-o tile, 16-row tile), 8 waves;
// wave = 2 output rows x 64o(2mi) x 64x(2ni), acc 2x2x2 f32x16 = 128 regs.
// K-loop: chunk = 16 ch, double-buffered LDS via global_load_lds.
// COMPUTE: software-pipelined (loads one 12-MFMA group ahead, distinct regs)
// + sched_group_barrier emission pinning. NO setprio in the K-loop: setprio
// is a side-effecting intrinsic that fences scheduling regions, which is what
// kept forcing the ds_reads back against their consumers in r4-r8 (VGPR=124
// every round). With the fences gone the scheduler can honor the pipeline.
//
// ws layout:
//   s    : f32[16*512]                 @ 0
//   deco : f32[16*512]                 @ 32768
//   q    : f32[512*512]                @ 65536
//   wb2  : bf16 frag-linear W          @ 1114112   (8 ot x 32 chunk x 18 (mi,t) x 64 lane x 16B)
//   xs2  : bf16 khalf-major X          @ 5832704   (16 b x 32 chunk x 64 y x 2 h x 64 xpos x 16B)

#define NCH 512

static constexpr float FC_GAIN_C = 0.04419417382415922f;   // 1/sqrt(512)
static constexpr float W_GAIN_C  = 0.014731391274719742f;  // 1/sqrt(512*9)

typedef float        f32x4  __attribute__((ext_vector_type(4)));
typedef float        f32x16 __attribute__((ext_vector_type(16)));
typedef short        s16x8  __attribute__((ext_vector_type(8)));
typedef unsigned int u32x4  __attribute__((ext_vector_type(4)));

__device__ __forceinline__ unsigned short f2bf(float f) {
    __hip_bfloat16 h = __float2bfloat16(f);
    return *reinterpret_cast<unsigned short*>(&h);
}

__device__ __forceinline__ void gld16(const void* g, void* l) {
    __builtin_amdgcn_global_load_lds(
        (const __attribute__((address_space(1))) unsigned int*)g,
        (__attribute__((address_space(3))) unsigned int*)(l), 16, 0, 0);
}

// ---------------- K1: s[b,i] = style[b,:] . fc_w[i,:] * FC_GAIN + fc_b[i] ----------------
__global__ void calc_s_kernel(const float* __restrict__ style,
                              const float* __restrict__ fc_w,
                              const float* __restrict__ fc_b,
                              float* __restrict__ s) {
    int gw   = (blockIdx.x * blockDim.x + threadIdx.x) >> 6;
    int lane = threadIdx.x & 63;
    int b = gw >> 9;
    int i = gw & 511;
    const float* st = style + b * NCH;
    const float* fw = fc_w + (size_t)i * NCH;
    float sum = 0.f;
    #pragma unroll
    for (int k = 0; k < NCH / 64; ++k)
        sum += st[lane + 64 * k] * fw[lane + 64 * k];
    #pragma unroll
    for (int off = 32; off >= 1; off >>= 1)
        sum += __shfl_xor(sum, off, 64);
    if (lane == 0)
        s[b * NCH + i] = sum * FC_GAIN_C + fc_b[i];
}

// ---------------- K2: q[o,i] and fragment-linear wb2 ------------------------------------
// wb2 unit: (((ot*32+chunk)*18 + mi*9 + t)*64 + lane)*8 + e
// content: W[o = ot*64 + mi*32 + (lane&31)][ci = chunk*16 + (lane>>5)*8 + e][tap t] * gain
__global__ void calc_q_wb2_kernel(const float* __restrict__ weight,
                                  float* __restrict__ q,
                                  unsigned short* __restrict__ wb2) {
    int o = blockIdx.x;        // 0..511
    int i = threadIdx.x;       // 0..511 (ci)
    int orel = o & 63, ot = o >> 6;
    int mi = orel >> 5, l31 = orel & 31;
    int chunk = i >> 4, kk = i & 15;
    int lane = (kk >> 3) * 32 + l31, e = kk & 7;
    const float* wp = weight + ((size_t)o * NCH + i) * 9;
    float qs = 0.f;
    #pragma unroll
    for (int t = 0; t < 9; ++t) {
        float v = wp[t] * W_GAIN_C;
        qs += v * v;
        wb2[((((size_t)(ot * 32 + chunk) * 18) + mi * 9 + t) * 64 + lane) * 8 + e] = f2bf(v);
    }
    q[(size_t)o * NCH + i] = qs;
}

// ---------------- K3: deco[b,o] = rsqrt( sum_i q[o,i]*s[b,i]^2 + 1e-8 ) -----------------
__global__ void calc_deco_kernel(const float* __restrict__ q,
                                 const float* __restrict__ s,
                                 float* __restrict__ deco) {
    int gw   = (blockIdx.x * blockDim.x + threadIdx.x) >> 6;
    int lane = threadIdx.x & 63;
    int b = gw >> 9;
    int o = gw & 511;
    const float* qp = q + (size_t)o * NCH;
    const float* sp = s + b * NCH;
    float sum = 0.f;
    #pragma unroll
    for (int k = 0; k < NCH / 64; ++k) {
        float sv = sp[lane + 64 * k];
        sum += qp[lane + 64 * k] * sv * sv;
    }
    #pragma unroll
    for (int off = 32; off >= 1; off >>= 1)
        sum += __shfl_xor(sum, off, 64);
    if (lane == 0)
        deco[b * NCH + o] = rsqrtf(sum + 1e-8f);
}

// ---------------- K4: xs2 = bf16(x * s), NCHW -> khalf-major slot layout ------------------
// xs2 unit: (((b*32+chunk)*64 + y)*2 + h)*64 + xpos ; content ch [chunk*16+h*8, +8) at (y,xpos)
__global__ __launch_bounds__(256)
void scale_x2_kernel(const float* __restrict__ x, const float* __restrict__ s,
                     unsigned short* __restrict__ xs2) {
    __shared__ float tlf[2][64][17];
    int blk = blockIdx.x;          // 512 = bi*32 + chunk
    int chunk = blk & 31, bi = blk >> 5;
    int t = threadIdx.x;
    int ch0 = chunk * 16;
    int cl = t >> 4, xq = (t & 15) * 4;
    float sv = s[bi * NCH + ch0 + cl];
    const float* xp = x + ((size_t)(bi * NCH + ch0 + cl)) * 4096 + xq;
    int p = t >> 7, tt = t & 127;
    int hf = tt >> 6, xpos = tt & 63;
    unsigned short* xout = xs2 + (size_t)(bi * 32 + chunk) * 64 * 2 * 64 * 8;
    for (int y2 = 0; y2 < 64; y2 += 2) {
        f32x4 a0 = *(const f32x4*)(xp + (size_t)y2 * 64);
        f32x4 a1 = *(const f32x4*)(xp + (size_t)(y2 + 1) * 64);
        #pragma unroll
        for (int j = 0; j < 4; ++j) {
            tlf[0][xq + j][cl] = a0[j] * sv;
            tlf[1][xq + j][cl] = a1[j] * sv;
        }
        __syncthreads();
        const float* src = &tlf[p][xpos][hf * 8];
        u32x4 v;
        #pragma unroll
        for (int j = 0; j < 4; ++j)
            v[j] = (unsigned)f2bf(src[2 * j]) | ((unsigned)f2bf(src[2 * j + 1]) << 16);
        *(u32x4*)(xout + (((size_t)(y2 + p) * 2 + hf) * 64 + xpos) * 8) = v;
        __syncthreads();
    }
}

// ---------------- K5: conv --------------------------------------------------------------
// LDS per buffer: W [18 (mi,t)][64 lane][16B] = 18432 B, X [18 rows][2 h][66 P][16B] = 38016 B.
#define W_SH 9216    // shorts per W buffer
#define X_SH 19008   // shorts per X buffer

// 54 DMA ids over 8 waves: 0..35 = X (r_=id>>1, h=id&1), 36..53 = W slot (id-36)
#define ISSUE(nc, WN, XN)                                                          \
    {                                                                              \
        _Pragma("unroll") for (int j = 0; j < 7; ++j) {                            \
            int id = wave + j * 8;                                                 \
            if (id < 36) {                                                         \
                int r_ = id >> 1, hf = id & 1, gy = y0 - 1 + r_;                   \
                if (gy >= 0 && gy < 64)                                            \
                    gld16(xsrc + ((((size_t)(nc) * 64 + gy) * 2 + hf) * 64 + lane) * 16, \
                          (XN) + r_ * 1056 + hf * 528 + 8);                        \
            } else if (id < 54) {                                                  \
                int u = id - 36;                                                   \
                gld16(wsrc + (((size_t)(nc) * 18 + u) * 64 + lane) * 16,           \
                      (WN) + u * 512);                                             \
            }                                                                      \
        }                                                                          \
    }

#define VMBAR()                                                                    \
    {                                                                              \
        asm volatile("s_waitcnt vmcnt(0)" ::: "memory");                           \
        __builtin_amdgcn_s_barrier();                                              \
        __builtin_amdgcn_sched_barrier(0);                                         \
    }

#define LOADBROW(DST, XC, RR)                                                      \
    _Pragma("unroll") for (int dx = 0; dx < 3; ++dx)                               \
        _Pragma("unroll") for (int ni = 0; ni < 2; ++ni)                           \
            DST[dx][ni] = *(const s16x8*)((XC) + (RR) * 1056 + bofs[dx][ni]);

#define LOADATY(DST, WC, K)                                                        \
    _Pragma("unroll") for (int dx = 0; dx < 3; ++dx)                               \
        _Pragma("unroll") for (int mi = 0; mi < 2; ++mi)                           \
            DST[dx][mi] = *(const s16x8*)((WC) + ((mi * 9 + 3 * (K) + dx) << 9) + (lane << 3));

// 12-MFMA group for output row R — NO setprio (it fences scheduling regions)
#define MMA12(AV, BV, R)                                                           \
    _Pragma("unroll") for (int dx = 0; dx < 3; ++dx)                               \
        _Pragma("unroll") for (int mi = 0; mi < 2; ++mi)                           \
            _Pragma("unroll") for (int ni = 0; ni < 2; ++ni)                       \
                acc[R][mi][ni] = __builtin_amdgcn_mfma_f32_32x32x16_bf16(          \
                    AV[dx][mi], BV[dx][ni], acc[R][mi][ni], 0, 0, 0);

#define SGB __builtin_amdgcn_sched_group_barrier
// masks: 0x8 = MFMA, 0x100 = DS_READ

// software-pipelined + emission-pinned: each read group emits one 12-MFMA
// cluster ahead of its consumer; lgkm waits are pre-satisfied.
#define COMPUTE(WC, XC, ...)                                                       \
    {                                                                              \
        s16x8 A0[3][2], A1[3][2], A2[3][2];                                        \
        s16x8 B0[3][2], B1[3][2], B2[3][2], B3[3][2];                              \
        LOADATY(A0, WC, 0);                                                        \
        LOADBROW(B0, XC, rbase + 0);                                               \
        LOADBROW(B1, XC, rbase + 1);                                               \
        __VA_ARGS__;                                                               \
        SGB(0x100, 18, 0);                                                         \
        MMA12(A0, B0, 0);                                                          \
        SGB(0x8, 12, 0);                                                           \
        LOADATY(A1, WC, 1);                                                        \
        SGB(0x100, 6, 0);                                                          \
        MMA12(A0, B1, 1);                                                          \
        SGB(0x8, 12, 0);                                                           \
        LOADBROW(B2, XC, rbase + 2);                                               \
        SGB(0x100, 6, 0);                                                          \
        MMA12(A1, B1, 0);                                                          \
        SGB(0x8, 12, 0);                                                           \
        LOADATY(A2, WC, 2);                                                        \
        SGB(0x100, 6, 0);                                                          \
        MMA12(A1, B2, 1);                                                          \
        SGB(0x8, 12, 0);                                                           \
        LOADBROW(B3, XC, rbase + 3);                                               \
        SGB(0x100, 6, 0);                                                          \
        MMA12(A2, B2, 0);                                                          \
        SGB(0x8, 12, 0);                                                           \
        MMA12(A2, B3, 1);                                                          \
        SGB(0x8, 12, 0);                                                           \
    }

__global__ __launch_bounds__(512, 2)
void conv_kernel(const unsigned short* __restrict__ xs2,
                 const unsigned short* __restrict__ wb2,
                 const float* __restrict__ deco,
                 float* __restrict__ out) {
    extern __shared__ unsigned short smem[];
    unsigned short* w0 = smem;
    unsigned short* x0 = smem + W_SH;
    unsigned short* w1 = smem + W_SH + X_SH;
    unsigned short* x1 = smem + 2 * W_SH + X_SH;

    int tid  = threadIdx.x;
    int lane = tid & 63, wave = tid >> 6;
    int r31  = lane & 31, hi = lane >> 5;

    int blk = blockIdx.x;
    int swz = (blk & 7) * 64 + (blk >> 3);     // XCD-chunked (512 % 8 == 0, bijective)
    int bi = swz >> 5, ot = (swz >> 2) & 7, yt = swz & 3;
    int o0 = ot * 64, y0 = yt * 16;
    int rbase = 2 * wave;

    // zero X buffers once: halo granules (P=0,65) and out-of-image rows stay 0
    {
        u32x4 z = {0u, 0u, 0u, 0u};
        for (int idx = tid; idx < X_SH / 8; idx += 512) {
            *(u32x4*)(x0 + idx * 8) = z;
            *(u32x4*)(x1 + idx * 8) = z;
        }
    }
    __syncthreads();

    const char* wsrc = (const char*)wb2 + (size_t)ot * 32 * 18 * 64 * 16;
    const char* xsrc = (const char*)xs2 + (size_t)bi * 32 * 64 * 2 * 64 * 16;

    // lane-linear B read offsets (shorts): row term added per read
    int bofs[3][2];
    #pragma unroll
    for (int dx = 0; dx < 3; ++dx)
        #pragma unroll
        for (int ni = 0; ni < 2; ++ni)
            bofs[dx][ni] = hi * 528 + (r31 + dx + 32 * ni) * 8;

    f32x16 acc[2][2][2];
    #pragma unroll
    for (int r = 0; r < 2; ++r)
        #pragma unroll
        for (int mi = 0; mi < 2; ++mi)
            #pragma unroll
            for (int ni = 0; ni < 2; ++ni)
                #pragma unroll
                for (int k = 0; k < 16; ++k) acc[r][mi][ni][k] = 0.f;

    ISSUE(0, w0, x0);

    #pragma unroll 1
    for (int c = 0; c < 32; c += 2) {
        VMBAR();                                   // chunk-c data landed everywhere
        COMPUTE(w0, x0, ISSUE(c + 1, w1, x1));
        VMBAR();
        COMPUTE(w1, x1, if (c + 2 < 32) ISSUE(c + 2, w0, x0));
    }

    // epilogue: scale by deco, store f32
    const float* dcp = deco + bi * NCH + o0;
    #pragma unroll
    for (int r = 0; r < 2; ++r) {
        int y = y0 + 2 * wave + r;
        #pragma unroll
        for (int mi = 0; mi < 2; ++mi) {
            #pragma unroll
            for (int rg = 0; rg < 16; ++rg) {
                int ol = mi * 32 + (rg & 3) + 8 * (rg >> 2) + 4 * hi;
                float dc = dcp[ol];
                float* orow = out + ((size_t)(bi * NCH + o0 + ol) * 64 + y) * 64 + r31;
                orow[0]  = acc[r][mi][0][rg] * dc;
                orow[32] = acc[r][mi][1][rg] * dc;
            }
        }
    }
}

extern "C" void kernel_launch(void* const* d_in, const int* in_sizes, int n_in,
                              void* d_out, int out_size, void* d_ws, size_t ws_size,
                              hipStream_t stream) {
    const float* x      = (const float*)d_in[0];
    const float* style  = (const float*)d_in[1];
    const float* weight = (const float*)d_in[2];
    const float* fc_w   = (const float*)d_in[3];
    const float* fc_b   = (const float*)d_in[4];
    float* out = (float*)d_out;

    char* ws = (char*)d_ws;
    float* s    = (float*)(ws);
    float* deco = (float*)(ws + 32768);
    float* q    = (float*)(ws + 65536);
    unsigned short* wb2 = (unsigned short*)(ws + 1114112);
    unsigned short* xs2 = (unsigned short*)(ws + 5832704);

    (void)hipFuncSetAttribute((const void*)conv_kernel,
                              hipFuncAttributeMaxDynamicSharedMemorySize, 112896);

    calc_s_kernel<<<2048, 256, 0, stream>>>(style, fc_w, fc_b, s);
    calc_q_wb2_kernel<<<512, 512, 0, stream>>>(weight, q, wb2);
    calc_deco_kernel<<<2048, 256, 0, stream>>>(q, s, deco);
    scale_x2_kernel<<<512, 256, 0, stream>>>(x, s, xs2);
    conv_kernel<<<512, 512, 112896, stream>>>(xs2, wb2, deco, out);
}

// Round 11
// 297.310 us; speedup vs baseline: 1.2012x; 1.0097x over previous
//
#include <hip/hip_runtime.h>
#include <hip/hip_bf16.h>

// ModulatedConv2d B=16, Cin=Cout=512, 3x3, 64x64.
// out = deco[b,o] * conv2d(x*s[b,i], W*gain), weights shared across batch.
// Conv: 32x32x16 bf16 MFMA. Block = (bi, 64-o tile, 16-row tile), 8 waves;
// wave = 2 output rows x 64o(2mi) x 64x(2ni), acc 2x2x2 f32x16 = 128 regs.
// K-loop: chunk = 16 ch, double-buffered LDS via global_load_lds.
// WAVE-PHASE DESYNC: the per-wave register cap (256 unified at 2 waves/SIMD;
// acc alone is 128) makes in-wave software pipelining unallocatable (r7-r10:
// VGPR pinned at 124 every attempt). Instead, co-resident waves on a SIMD run
// the tap-row groups in OPPOSITE order ((w^(w>>2))&1 picks fwd/rev), so one
// wave's ds_read burst overlaps the other's setprio'd MFMA cluster (m114
// cross-wave overlap; T5 gets real role diversity).
//
// ws layout:
//   s    : f32[16*512]                 @ 0
//   deco : f32[16*512]                 @ 32768
//   q    : f32[512*512]                @ 65536
//   wb2  : bf16 frag-linear W          @ 1114112   (8 ot x 32 chunk x 18 (mi,t) x 64 lane x 16B)
//   xs2  : bf16 khalf-major X          @ 5832704   (16 b x 32 chunk x 64 y x 2 h x 64 xpos x 16B)

#define NCH 512

static constexpr float FC_GAIN_C = 0.04419417382415922f;   // 1/sqrt(512)
static constexpr float W_GAIN_C  = 0.014731391274719742f;  // 1/sqrt(512*9)

typedef float        f32x4  __attribute__((ext_vector_type(4)));
typedef float        f32x16 __attribute__((ext_vector_type(16)));
typedef short        s16x8  __attribute__((ext_vector_type(8)));
typedef unsigned int u32x4  __attribute__((ext_vector_type(4)));

__device__ __forceinline__ unsigned short f2bf(float f) {
    __hip_bfloat16 h = __float2bfloat16(f);
    return *reinterpret_cast<unsigned short*>(&h);
}

__device__ __forceinline__ void gld16(const void* g, void* l) {
    __builtin_amdgcn_global_load_lds(
        (const __attribute__((address_space(1))) unsigned int*)g,
        (__attribute__((address_space(3))) unsigned int*)(l), 16, 0, 0);
}

// ---------------- K1: s[b,i] = style[b,:] . fc_w[i,:] * FC_GAIN + fc_b[i] ----------------
__global__ void calc_s_kernel(const float* __restrict__ style,
                              const float* __restrict__ fc_w,
                              const float* __restrict__ fc_b,
                              float* __restrict__ s) {
    int gw   = (blockIdx.x * blockDim.x + threadIdx.x) >> 6;
    int lane = threadIdx.x & 63;
    int b = gw >> 9;
    int i = gw & 511;
    const float* st = style + b * NCH;
    const float* fw = fc_w + (size_t)i * NCH;
    float sum = 0.f;
    #pragma unroll
    for (int k = 0; k < NCH / 64; ++k)
        sum += st[lane + 64 * k] * fw[lane + 64 * k];
    #pragma unroll
    for (int off = 32; off >= 1; off >>= 1)
        sum += __shfl_xor(sum, off, 64);
    if (lane == 0)
        s[b * NCH + i] = sum * FC_GAIN_C + fc_b[i];
}

// ---------------- K2: q[o,i] and fragment-linear wb2 ------------------------------------
// wb2 unit: (((ot*32+chunk)*18 + mi*9 + t)*64 + lane)*8 + e
// content: W[o = ot*64 + mi*32 + (lane&31)][ci = chunk*16 + (lane>>5)*8 + e][tap t] * gain
__global__ void calc_q_wb2_kernel(const float* __restrict__ weight,
                                  float* __restrict__ q,
                                  unsigned short* __restrict__ wb2) {
    int o = blockIdx.x;        // 0..511
    int i = threadIdx.x;       // 0..511 (ci)
    int orel = o & 63, ot = o >> 6;
    int mi = orel >> 5, l31 = orel & 31;
    int chunk = i >> 4, kk = i & 15;
    int lane = (kk >> 3) * 32 + l31, e = kk & 7;
    const float* wp = weight + ((size_t)o * NCH + i) * 9;
    float qs = 0.f;
    #pragma unroll
    for (int t = 0; t < 9; ++t) {
        float v = wp[t] * W_GAIN_C;
        qs += v * v;
        wb2[((((size_t)(ot * 32 + chunk) * 18) + mi * 9 + t) * 64 + lane) * 8 + e] = f2bf(v);
    }
    q[(size_t)o * NCH + i] = qs;
}

// ---------------- K3: deco[b,o] = rsqrt( sum_i q[o,i]*s[b,i]^2 + 1e-8 ) -----------------
__global__ void calc_deco_kernel(const float* __restrict__ q,
                                 const float* __restrict__ s,
                                 float* __restrict__ deco) {
    int gw   = (blockIdx.x * blockDim.x + threadIdx.x) >> 6;
    int lane = threadIdx.x & 63;
    int b = gw >> 9;
    int o = gw & 511;
    const float* qp = q + (size_t)o * NCH;
    const float* sp = s + b * NCH;
    float sum = 0.f;
    #pragma unroll
    for (int k = 0; k < NCH / 64; ++k) {
        float sv = sp[lane + 64 * k];
        sum += qp[lane + 64 * k] * sv * sv;
    }
    #pragma unroll
    for (int off = 32; off >= 1; off >>= 1)
        sum += __shfl_xor(sum, off, 64);
    if (lane == 0)
        deco[b * NCH + o] = rsqrtf(sum + 1e-8f);
}

// ---------------- K4: xs2 = bf16(x * s), NCHW -> khalf-major slot layout ------------------
// xs2 unit: (((b*32+chunk)*64 + y)*2 + h)*64 + xpos ; content ch [chunk*16+h*8, +8) at (y,xpos)
// grid 2048: blk = ((bi*32+chunk)*4 + yq); each block covers 16 y-rows.
__global__ __launch_bounds__(256)
void scale_x2_kernel(const float* __restrict__ x, const float* __restrict__ s,
                     unsigned short* __restrict__ xs2) {
    __shared__ float tlf[2][64][17];
    int blk = blockIdx.x;
    int yq  = blk & 3;
    int rest = blk >> 2;           // bi*32 + chunk
    int chunk = rest & 31, bi = rest >> 5;
    int t = threadIdx.x;
    int ch0 = chunk * 16;
    int cl = t >> 4, xq = (t & 15) * 4;
    float sv = s[bi * NCH + ch0 + cl];
    const float* xp = x + ((size_t)(bi * NCH + ch0 + cl)) * 4096 + xq;
    int p = t >> 7, tt = t & 127;
    int hf = tt >> 6, xpos = tt & 63;
    unsigned short* xout = xs2 + (size_t)(bi * 32 + chunk) * 64 * 2 * 64 * 8;
    int y_lo = yq * 16, y_hi = y_lo + 16;
    for (int y2 = y_lo; y2 < y_hi; y2 += 2) {
        f32x4 a0 = *(const f32x4*)(xp + (size_t)y2 * 64);
        f32x4 a1 = *(const f32x4*)(xp + (size_t)(y2 + 1) * 64);
        #pragma unroll
        for (int j = 0; j < 4; ++j) {
            tlf[0][xq + j][cl] = a0[j] * sv;
            tlf[1][xq + j][cl] = a1[j] * sv;
        }
        __syncthreads();
        const float* src = &tlf[p][xpos][hf * 8];
        u32x4 v;
        #pragma unroll
        for (int j = 0; j < 4; ++j)
            v[j] = (unsigned)f2bf(src[2 * j]) | ((unsigned)f2bf(src[2 * j + 1]) << 16);
        *(u32x4*)(xout + (((size_t)(y2 + p) * 2 + hf) * 64 + xpos) * 8) = v;
        __syncthreads();
    }
}

// ---------------- K5: conv --------------------------------------------------------------
// LDS per buffer: W [18 (mi,t)][64 lane][16B] = 18432 B, X [18 rows][2 h][66 P][16B] = 38016 B.
#define W_SH 9216    // shorts per W buffer
#define X_SH 19008   // shorts per X buffer

// 54 DMA ids over 8 waves: 0..35 = X (r_=id>>1, h=id&1), 36..53 = W slot (id-36)
#define ISSUE(nc, WN, XN)                                                          \
    {                                                                              \
        _Pragma("unroll") for (int j = 0; j < 7; ++j) {                            \
            int id = wave + j * 8;                                                 \
            if (id < 36) {                                                         \
                int r_ = id >> 1, hf = id & 1, gy = y0 - 1 + r_;                   \
                if (gy >= 0 && gy < 64)                                            \
                    gld16(xsrc + ((((size_t)(nc) * 64 + gy) * 2 + hf) * 64 + lane) * 16, \
                          (XN) + r_ * 1056 + hf * 528 + 8);                        \
            } else if (id < 54) {                                                  \
                int u = id - 36;                                                   \
                gld16(wsrc + (((size_t)(nc) * 18 + u) * 64 + lane) * 16,           \
                      (WN) + u * 512);                                             \
            }                                                                      \
        }                                                                          \
    }

#define VMBAR()                                                                    \
    {                                                                              \
        asm volatile("s_waitcnt vmcnt(0)" ::: "memory");                           \
        __builtin_amdgcn_s_barrier();                                              \
        __builtin_amdgcn_sched_barrier(0);                                         \
    }

#define LOADBROW(DST, XC, RR)                                                      \
    _Pragma("unroll") for (int dx = 0; dx < 3; ++dx)                               \
        _Pragma("unroll") for (int ni = 0; ni < 2; ++ni)                           \
            DST[dx][ni] = *(const s16x8*)((XC) + (RR) * 1056 + bofs[dx][ni]);

#define LOADATY(DST, WC, K)                                                        \
    _Pragma("unroll") for (int dx = 0; dx < 3; ++dx)                               \
        _Pragma("unroll") for (int mi = 0; mi < 2; ++mi)                           \
            DST[dx][mi] = *(const s16x8*)((WC) + ((mi * 9 + 3 * (K) + dx) << 9) + (lane << 3));

// 12-MFMA cluster for output row R; setprio so the MFMA-phase wave wins
// SIMD arbitration against the counter-phased read-bursting wave.
#define MMA12(AV, BV, R)                                                           \
    __builtin_amdgcn_s_setprio(1);                                                 \
    _Pragma("unroll") for (int dx = 0; dx < 3; ++dx)                               \
        _Pragma("unroll") for (int mi = 0; mi < 2; ++mi)                           \
            _Pragma("unroll") for (int ni = 0; ni < 2; ++ni)                       \
                acc[R][mi][ni] = __builtin_amdgcn_mfma_f32_32x32x16_bf16(          \
                    AV[dx][mi], BV[dx][ni], acc[R][mi][ni], 0, 0, 0);              \
    __builtin_amdgcn_s_setprio(0);

// forward tap-row order: groups (0,1,2)
#define COMPUTE_FWD(WC, XC, ...)                                                   \
    {                                                                              \
        s16x8 A0[3][2], A1[3][2], A2[3][2];                                        \
        s16x8 B0[3][2], B1[3][2], B2[3][2], B3[3][2];                              \
        LOADATY(A0, WC, 0);                                                        \
        LOADBROW(B0, XC, rbase + 0);                                               \
        LOADBROW(B1, XC, rbase + 1);                                               \
        __VA_ARGS__;                                                               \
        MMA12(A0, B0, 0);                                                          \
        LOADATY(A1, WC, 1);                                                        \
        MMA12(A0, B1, 1);                                                          \
        LOADBROW(B2, XC, rbase + 2);                                               \
        MMA12(A1, B1, 0);                                                          \
        LOADATY(A2, WC, 2);                                                        \
        MMA12(A1, B2, 1);                                                          \
        LOADBROW(B3, XC, rbase + 3);                                               \
        MMA12(A2, B2, 0);                                                          \
        MMA12(A2, B3, 1);                                                          \
    }

// reverse tap-row order: groups (2,1,0) — counter-phases the paired wave
#define COMPUTE_REV(WC, XC, ...)                                                   \
    {                                                                              \
        s16x8 A0[3][2], A1[3][2], A2[3][2];                                        \
        s16x8 B0[3][2], B1[3][2], B2[3][2], B3[3][2];                              \
        LOADATY(A2, WC, 2);                                                        \
        LOADBROW(B3, XC, rbase + 3);                                               \
        LOADBROW(B2, XC, rbase + 2);                                               \
        __VA_ARGS__;                                                               \
        MMA12(A2, B3, 1);                                                          \
        LOADATY(A1, WC, 1);                                                        \
        MMA12(A2, B2, 0);                                                          \
        LOADBROW(B1, XC, rbase + 1);                                               \
        MMA12(A1, B2, 1);                                                          \
        LOADATY(A0, WC, 0);                                                        \
        MMA12(A1, B1, 0);                                                          \
        LOADBROW(B0, XC, rbase + 0);                                               \
        MMA12(A0, B1, 1);                                                          \
        MMA12(A0, B0, 0);                                                          \
    }

__global__ __launch_bounds__(512, 2)
void conv_kernel(const unsigned short* __restrict__ xs2,
                 const unsigned short* __restrict__ wb2,
                 const float* __restrict__ deco,
                 float* __restrict__ out) {
    extern __shared__ unsigned short smem[];
    unsigned short* w0 = smem;
    unsigned short* x0 = smem + W_SH;
    unsigned short* w1 = smem + W_SH + X_SH;
    unsigned short* x1 = smem + 2 * W_SH + X_SH;

    int tid  = threadIdx.x;
    int lane = tid & 63, wave = tid >> 6;
    int r31  = lane & 31, hi = lane >> 5;

    int blk = blockIdx.x;
    int swz = (blk & 7) * 64 + (blk >> 3);     // XCD-chunked (512 % 8 == 0, bijective)
    int bi = swz >> 5, ot = (swz >> 2) & 7, yt = swz & 3;
    int o0 = ot * 64, y0 = yt * 16;
    int rbase = 2 * wave;
    // counter-phase split: differs for wave pairs under both w%4 and w>>1 mappings
    bool fwd = (((wave ^ (wave >> 2)) & 1) == 0);

    // zero X buffers once: halo granules (P=0,65) and out-of-image rows stay 0
    {
        u32x4 z = {0u, 0u, 0u, 0u};
        for (int idx = tid; idx < X_SH / 8; idx += 512) {
            *(u32x4*)(x0 + idx * 8) = z;
            *(u32x4*)(x1 + idx * 8) = z;
        }
    }
    __syncthreads();

    const char* wsrc = (const char*)wb2 + (size_t)ot * 32 * 18 * 64 * 16;
    const char* xsrc = (const char*)xs2 + (size_t)bi * 32 * 64 * 2 * 64 * 16;

    // lane-linear B read offsets (shorts): row term added per read
    int bofs[3][2];
    #pragma unroll
    for (int dx = 0; dx < 3; ++dx)
        #pragma unroll
        for (int ni = 0; ni < 2; ++ni)
            bofs[dx][ni] = hi * 528 + (r31 + dx + 32 * ni) * 8;

    f32x16 acc[2][2][2];
    #pragma unroll
    for (int r = 0; r < 2; ++r)
        #pragma unroll
        for (int mi = 0; mi < 2; ++mi)
            #pragma unroll
            for (int ni = 0; ni < 2; ++ni)
                #pragma unroll
                for (int k = 0; k < 16; ++k) acc[r][mi][ni][k] = 0.f;

    ISSUE(0, w0, x0);

    #pragma unroll 1
    for (int c = 0; c < 32; c += 2) {
        VMBAR();                                   // chunk-c data landed everywhere
        if (fwd) {
            COMPUTE_FWD(w0, x0, ISSUE(c + 1, w1, x1));
        } else {
            COMPUTE_REV(w0, x0, ISSUE(c + 1, w1, x1));
        }
        VMBAR();
        if (fwd) {
            COMPUTE_FWD(w1, x1, if (c + 2 < 32) ISSUE(c + 2, w0, x0));
        } else {
            COMPUTE_REV(w1, x1, if (c + 2 < 32) ISSUE(c + 2, w0, x0));
        }
    }

    // epilogue: scale by deco, store f32
    const float* dcp = deco + bi * NCH + o0;
    #pragma unroll
    for (int r = 0; r < 2; ++r) {
        int y = y0 + 2 * wave + r;
        #pragma unroll
        for (int mi = 0; mi < 2; ++mi) {
            #pragma unroll
            for (int rg = 0; rg < 16; ++rg) {
                int ol = mi * 32 + (rg & 3) + 8 * (rg >> 2) + 4 * hi;
                float dc = dcp[ol];
                float* orow = out + ((size_t)(bi * NCH + o0 + ol) * 64 + y) * 64 + r31;
                orow[0]  = acc[r][mi][0][rg] * dc;
                orow[32] = acc[r][mi][1][rg] * dc;
            }
        }
    }
}

extern "C" void kernel_launch(void* const* d_in, const int* in_sizes, int n_in,
                              void* d_out, int out_size, void* d_ws, size_t ws_size,
                              hipStream_t stream) {
    const float* x      = (const float*)d_in[0];
    const float* style  = (const float*)d_in[1];
    const float* weight = (const float*)d_in[2];
    const float* fc_w   = (const float*)d_in[3];
    const float* fc_b   = (const float*)d_in[4];
    float* out = (float*)d_out;

    char* ws = (char*)d_ws;
    float* s    = (float*)(ws);
    float* deco = (float*)(ws + 32768);
    float* q    = (float*)(ws + 65536);
    unsigned short* wb2 = (unsigned short*)(ws + 1114112);
    unsigned short* xs2 = (unsigned short*)(ws + 5832704);

    (void)hipFuncSetAttribute((const void*)conv_kernel,
                              hipFuncAttributeMaxDynamicSharedMemorySize, 112896);

    calc_s_kernel<<<2048, 256, 0, stream>>>(style, fc_w, fc_b, s);
    calc_q_wb2_kernel<<<512, 512, 0, stream>>>(weight, q, wb2);
    calc_deco_kernel<<<2048, 256, 0, stream>>>(q, s, deco);
    scale_x2_kernel<<<2048, 256, 0, stream>>>(x, s, xs2);
    conv_kernel<<<512, 512, 112896, stream>>>(xs2, wb2, deco, out);
}

// Round 12
// 292.853 us; speedup vs baseline: 1.2195x; 1.0152x over previous
//
#include <hip/hip_runtime.h>
#include <hip/hip_bf16.h>

// ModulatedConv2d B=16, Cin=Cout=512, 3x3, 64x64.
// out = deco[b,o] * conv2d(x*s[b,i], W*gain), weights shared across batch.
// Conv: 32x32x16 bf16 MFMA. Block = (bi, 64-o tile, 16-row tile), 8 waves;
// wave = 2 output rows x 64o(2mi) x 64x(2ni), acc 2x2x2 f32x16 = 128 regs.
// Rolling 4-row B window -> 42 ds_read_b128 per 72 MFMA per wave-chunk.
// This is the measured optimum of the configuration space (r2-r11):
//   per-CU chunk cost == MFMA(4648cyc) + LDS-reads(4032) + DMA(432), exactly
//   serialized; all overlap attempts are blocked by the 256-reg/wave cap at
//   2 waves/SIMD (acc=128 + pipeline liveness > cap -> loads get sunk).
//
// ws layout:
//   s    : f32[16*512]                 @ 0
//   deco : f32[16*512]                 @ 32768
//   q    : f32[512*512]                @ 65536
//   wb2  : bf16 frag-linear W          @ 1114112   (8 ot x 32 chunk x 18 (mi,t) x 64 lane x 16B)
//   xs2  : bf16 khalf-major X          @ 5832704   (16 b x 32 chunk x 64 y x 2 h x 64 xpos x 16B)

#define NCH 512

static constexpr float FC_GAIN_C = 0.04419417382415922f;   // 1/sqrt(512)
static constexpr float W_GAIN_C  = 0.014731391274719742f;  // 1/sqrt(512*9)

typedef float        f32x4  __attribute__((ext_vector_type(4)));
typedef float        f32x16 __attribute__((ext_vector_type(16)));
typedef short        s16x8  __attribute__((ext_vector_type(8)));
typedef unsigned int u32x4  __attribute__((ext_vector_type(4)));

__device__ __forceinline__ unsigned short f2bf(float f) {
    __hip_bfloat16 h = __float2bfloat16(f);
    return *reinterpret_cast<unsigned short*>(&h);
}

__device__ __forceinline__ void gld16(const void* g, void* l) {
    __builtin_amdgcn_global_load_lds(
        (const __attribute__((address_space(1))) unsigned int*)g,
        (__attribute__((address_space(3))) unsigned int*)(l), 16, 0, 0);
}

// ---------------- K1: s[b,i] = style[b,:] . fc_w[i,:] * FC_GAIN + fc_b[i] ----------------
__global__ void calc_s_kernel(const float* __restrict__ style,
                              const float* __restrict__ fc_w,
                              const float* __restrict__ fc_b,
                              float* __restrict__ s) {
    int gw   = (blockIdx.x * blockDim.x + threadIdx.x) >> 6;
    int lane = threadIdx.x & 63;
    int b = gw >> 9;
    int i = gw & 511;
    const float* st = style + b * NCH;
    const float* fw = fc_w + (size_t)i * NCH;
    float sum = 0.f;
    #pragma unroll
    for (int k = 0; k < NCH / 64; ++k)
        sum += st[lane + 64 * k] * fw[lane + 64 * k];
    #pragma unroll
    for (int off = 32; off >= 1; off >>= 1)
        sum += __shfl_xor(sum, off, 64);
    if (lane == 0)
        s[b * NCH + i] = sum * FC_GAIN_C + fc_b[i];
}

// ---------------- K2: q[o,i] and fragment-linear wb2 ------------------------------------
// wb2 unit: (((ot*32+chunk)*18 + mi*9 + t)*64 + lane)*8 + e
// content: W[o = ot*64 + mi*32 + (lane&31)][ci = chunk*16 + (lane>>5)*8 + e][tap t] * gain
__global__ void calc_q_wb2_kernel(const float* __restrict__ weight,
                                  float* __restrict__ q,
                                  unsigned short* __restrict__ wb2) {
    int o = blockIdx.x;        // 0..511
    int i = threadIdx.x;       // 0..511 (ci)
    int orel = o & 63, ot = o >> 6;
    int mi = orel >> 5, l31 = orel & 31;
    int chunk = i >> 4, kk = i & 15;
    int lane = (kk >> 3) * 32 + l31, e = kk & 7;
    const float* wp = weight + ((size_t)o * NCH + i) * 9;
    float qs = 0.f;
    #pragma unroll
    for (int t = 0; t < 9; ++t) {
        float v = wp[t] * W_GAIN_C;
        qs += v * v;
        wb2[((((size_t)(ot * 32 + chunk) * 18) + mi * 9 + t) * 64 + lane) * 8 + e] = f2bf(v);
    }
    q[(size_t)o * NCH + i] = qs;
}

// ---------------- K3: deco[b,o] = rsqrt( sum_i q[o,i]*s[b,i]^2 + 1e-8 ) -----------------
__global__ void calc_deco_kernel(const float* __restrict__ q,
                                 const float* __restrict__ s,
                                 float* __restrict__ deco) {
    int gw   = (blockIdx.x * blockDim.x + threadIdx.x) >> 6;
    int lane = threadIdx.x & 63;
    int b = gw >> 9;
    int o = gw & 511;
    const float* qp = q + (size_t)o * NCH;
    const float* sp = s + b * NCH;
    float sum = 0.f;
    #pragma unroll
    for (int k = 0; k < NCH / 64; ++k) {
        float sv = sp[lane + 64 * k];
        sum += qp[lane + 64 * k] * sv * sv;
    }
    #pragma unroll
    for (int off = 32; off >= 1; off >>= 1)
        sum += __shfl_xor(sum, off, 64);
    if (lane == 0)
        deco[b * NCH + o] = rsqrtf(sum + 1e-8f);
}

// ---------------- K4: xs2 = bf16(x * s), NCHW -> khalf-major slot layout ------------------
// xs2 unit: (((b*32+chunk)*64 + y)*2 + h)*64 + xpos ; content ch [chunk*16+h*8, +8) at (y,xpos)
// grid 2048: blk = ((bi*32+chunk)*4 + yq); each block covers 16 y-rows.
__global__ __launch_bounds__(256)
void scale_x2_kernel(const float* __restrict__ x, const float* __restrict__ s,
                     unsigned short* __restrict__ xs2) {
    __shared__ float tlf[2][64][17];
    int blk = blockIdx.x;
    int yq  = blk & 3;
    int rest = blk >> 2;           // bi*32 + chunk
    int chunk = rest & 31, bi = rest >> 5;
    int t = threadIdx.x;
    int ch0 = chunk * 16;
    int cl = t >> 4, xq = (t & 15) * 4;
    float sv = s[bi * NCH + ch0 + cl];
    const float* xp = x + ((size_t)(bi * NCH + ch0 + cl)) * 4096 + xq;
    int p = t >> 7, tt = t & 127;
    int hf = tt >> 6, xpos = tt & 63;
    unsigned short* xout = xs2 + (size_t)(bi * 32 + chunk) * 64 * 2 * 64 * 8;
    int y_lo = yq * 16, y_hi = y_lo + 16;
    for (int y2 = y_lo; y2 < y_hi; y2 += 2) {
        f32x4 a0 = *(const f32x4*)(xp + (size_t)y2 * 64);
        f32x4 a1 = *(const f32x4*)(xp + (size_t)(y2 + 1) * 64);
        #pragma unroll
        for (int j = 0; j < 4; ++j) {
            tlf[0][xq + j][cl] = a0[j] * sv;
            tlf[1][xq + j][cl] = a1[j] * sv;
        }
        __syncthreads();
        const float* src = &tlf[p][xpos][hf * 8];
        u32x4 v;
        #pragma unroll
        for (int j = 0; j < 4; ++j)
            v[j] = (unsigned)f2bf(src[2 * j]) | ((unsigned)f2bf(src[2 * j + 1]) << 16);
        *(u32x4*)(xout + (((size_t)(y2 + p) * 2 + hf) * 64 + xpos) * 8) = v;
        __syncthreads();
    }
}

// ---------------- K5: conv (r4-exact, the measured optimum) -------------------------------
// LDS per buffer: W [18 (mi,t)][64 lane][16B] = 18432 B, X [18 rows][2 h][66 P][16B] = 38016 B.
#define W_SH 9216    // shorts per W buffer
#define X_SH 19008   // shorts per X buffer

// 54 DMA ids over 8 waves: 0..35 = X (r_=id>>1, h=id&1), 36..53 = W slot (id-36)
#define ISSUE(nc, WN, XN)                                                          \
    {                                                                              \
        _Pragma("unroll") for (int j = 0; j < 7; ++j) {                            \
            int id = wave + j * 8;                                                 \
            if (id < 36) {                                                         \
                int r_ = id >> 1, hf = id & 1, gy = y0 - 1 + r_;                   \
                if (gy >= 0 && gy < 64)                                            \
                    gld16(xsrc + ((((size_t)(nc) * 64 + gy) * 2 + hf) * 64 + lane) * 16, \
                          (XN) + r_ * 1056 + hf * 528 + 8);                        \
            } else if (id < 54) {                                                  \
                int u = id - 36;                                                   \
                gld16(wsrc + (((size_t)(nc) * 18 + u) * 64 + lane) * 16,           \
                      (WN) + u * 512);                                             \
            }                                                                      \
        }                                                                          \
    }

#define VMBAR()                                                                    \
    {                                                                              \
        asm volatile("s_waitcnt vmcnt(0)" ::: "memory");                           \
        __builtin_amdgcn_s_barrier();                                              \
        __builtin_amdgcn_sched_barrier(0);                                         \
    }

#define LOADB(DST, XC, RR)                                                         \
    _Pragma("unroll") for (int dx = 0; dx < 3; ++dx)                               \
        _Pragma("unroll") for (int ni = 0; ni < 2; ++ni)                           \
            DST[dx][ni] = *(const s16x8*)((XC) + (RR) * 1056 + bofs[dx][ni]);

#define LOADA(DST, WC, K)                                                          \
    _Pragma("unroll") for (int dx = 0; dx < 3; ++dx)                               \
        _Pragma("unroll") for (int mi = 0; mi < 2; ++mi)                           \
            DST[dx][mi] = *(const s16x8*)((WC) + ((mi * 9 + 3 * (K) + dx) << 9) + (lane << 3));

#define MMA(AV, B0, B1)                                                            \
    _Pragma("unroll") for (int dx = 0; dx < 3; ++dx)                               \
        _Pragma("unroll") for (int mi = 0; mi < 2; ++mi)                           \
            _Pragma("unroll") for (int ni = 0; ni < 2; ++ni) {                     \
                acc[0][mi][ni] = __builtin_amdgcn_mfma_f32_32x32x16_bf16(          \
                    AV[dx][mi], B0[dx][ni], acc[0][mi][ni], 0, 0, 0);              \
                acc[1][mi][ni] = __builtin_amdgcn_mfma_f32_32x32x16_bf16(          \
                    AV[dx][mi], B1[dx][ni], acc[1][mi][ni], 0, 0, 0);              \
            }

// rolling 2-row B window: rows rbase..rbase+3; W frags shared by both output rows
#define COMPUTE(WC, XC, ...)                                                       \
    {                                                                              \
        s16x8 Pb[3][2], Qb[3][2], Af[3][2];                                        \
        LOADB(Pb, XC, rbase + 0);                                                  \
        LOADB(Qb, XC, rbase + 1);                                                  \
        LOADA(Af, WC, 0);                                                          \
        __VA_ARGS__;                                                               \
        MMA(Af, Pb, Qb);                                                           \
        LOADB(Pb, XC, rbase + 2);                                                  \
        LOADA(Af, WC, 1);                                                          \
        MMA(Af, Qb, Pb);                                                           \
        LOADB(Qb, XC, rbase + 3);                                                  \
        LOADA(Af, WC, 2);                                                          \
        MMA(Af, Pb, Qb);                                                           \
    }

__global__ __launch_bounds__(512, 2)
void conv_kernel(const unsigned short* __restrict__ xs2,
                 const unsigned short* __restrict__ wb2,
                 const float* __restrict__ deco,
                 float* __restrict__ out) {
    extern __shared__ unsigned short smem[];
    unsigned short* w0 = smem;
    unsigned short* x0 = smem + W_SH;
    unsigned short* w1 = smem + W_SH + X_SH;
    unsigned short* x1 = smem + 2 * W_SH + X_SH;

    int tid  = threadIdx.x;
    int lane = tid & 63, wave = tid >> 6;
    int r31  = lane & 31, hi = lane >> 5;

    int blk = blockIdx.x;
    int swz = (blk & 7) * 64 + (blk >> 3);     // XCD-chunked (512 % 8 == 0, bijective)
    int bi = swz >> 5, ot = (swz >> 2) & 7, yt = swz & 3;
    int o0 = ot * 64, y0 = yt * 16;
    int rbase = 2 * wave;

    // zero X buffers once: halo granules (P=0,65) and out-of-image rows stay 0
    {
        u32x4 z = {0u, 0u, 0u, 0u};
        for (int idx = tid; idx < X_SH / 8; idx += 512) {
            *(u32x4*)(x0 + idx * 8) = z;
            *(u32x4*)(x1 + idx * 8) = z;
        }
    }
    __syncthreads();

    const char* wsrc = (const char*)wb2 + (size_t)ot * 32 * 18 * 64 * 16;
    const char* xsrc = (const char*)xs2 + (size_t)bi * 32 * 64 * 2 * 64 * 16;

    // lane-linear B read offsets (shorts): row term added per read
    int bofs[3][2];
    #pragma unroll
    for (int dx = 0; dx < 3; ++dx)
        #pragma unroll
        for (int ni = 0; ni < 2; ++ni)
            bofs[dx][ni] = hi * 528 + (r31 + dx + 32 * ni) * 8;

    f32x16 acc[2][2][2];
    #pragma unroll
    for (int r = 0; r < 2; ++r)
        #pragma unroll
        for (int mi = 0; mi < 2; ++mi)
            #pragma unroll
            for (int ni = 0; ni < 2; ++ni)
                #pragma unroll
                for (int k = 0; k < 16; ++k) acc[r][mi][ni][k] = 0.f;

    ISSUE(0, w0, x0);

    #pragma unroll 1
    for (int c = 0; c < 32; c += 2) {
        VMBAR();                                   // chunk-c data landed everywhere
        COMPUTE(w0, x0, ISSUE(c + 1, w1, x1));
        VMBAR();
        COMPUTE(w1, x1, if (c + 2 < 32) ISSUE(c + 2, w0, x0));
    }

    // epilogue: scale by deco, store f32
    const float* dcp = deco + bi * NCH + o0;
    #pragma unroll
    for (int r = 0; r < 2; ++r) {
        int y = y0 + 2 * wave + r;
        #pragma unroll
        for (int mi = 0; mi < 2; ++mi) {
            #pragma unroll
            for (int rg = 0; rg < 16; ++rg) {
                int ol = mi * 32 + (rg & 3) + 8 * (rg >> 2) + 4 * hi;
                float dc = dcp[ol];
                float* orow = out + ((size_t)(bi * NCH + o0 + ol) * 64 + y) * 64 + r31;
                orow[0]  = acc[r][mi][0][rg] * dc;
                orow[32] = acc[r][mi][1][rg] * dc;
            }
        }
    }
}

extern "C" void kernel_launch(void* const* d_in, const int* in_sizes, int n_in,
                              void* d_out, int out_size, void* d_ws, size_t ws_size,
                              hipStream_t stream) {
    const float* x      = (const float*)d_in[0];
    const float* style  = (const float*)d_in[1];
    const float* weight = (const float*)d_in[2];
    const float* fc_w   = (const float*)d_in[3];
    const float* fc_b   = (const float*)d_in[4];
    float* out = (float*)d_out;

    char* ws = (char*)d_ws;
    float* s    = (float*)(ws);
    float* deco = (float*)(ws + 32768);
    float* q    = (float*)(ws + 65536);
    unsigned short* wb2 = (unsigned short*)(ws + 1114112);
    unsigned short* xs2 = (unsigned short*)(ws + 5832704);

    (void)hipFuncSetAttribute((const void*)conv_kernel,
                              hipFuncAttributeMaxDynamicSharedMemorySize, 112896);

    calc_s_kernel<<<2048, 256, 0, stream>>>(style, fc_w, fc_b, s);
    calc_q_wb2_kernel<<<512, 512, 0, stream>>>(weight, q, wb2);
    calc_deco_kernel<<<2048, 256, 0, stream>>>(q, s, deco);
    scale_x2_kernel<<<2048, 256, 0, stream>>>(x, s, xs2);
    conv_kernel<<<512, 512, 112896, stream>>>(xs2, wb2, deco, out);
}